// Round 11
// baseline (1427.357 us; speedup 1.0000x reference)
//
#include <hip/hip_runtime.h>
#include <hip/hip_bf16.h>

#define NB 16
#define NC 64
#define C2 32
#define C4 16
#define HH 256
#define WW 256
#define HW (HH*WW)          // 65536

typedef unsigned short u16;
typedef u16 u16x8 __attribute__((ext_vector_type(8)));
typedef u16 u16x4 __attribute__((ext_vector_type(4)));
typedef float f4v __attribute__((ext_vector_type(4)));

// ws layout (floats):
//   [0, 2048)        w1T   : w1T[c*32+o] = w1[o*64+c]
//   [2048, 10240)    qkv   : [b][ch32][s16]
//   [26624, 30720)   gates : [b][o16][s16]   (per-b stride 256)
//   [32768, ...)     y     : bf16 [b][o32][h256][w256]  (67.1 MB)

__global__ __launch_bounds__(256) void prep_kernel(const float* __restrict__ w1,
                                                   float* __restrict__ ws) {
    int t = threadIdx.x;
    for (int i = t; i < 2048; i += 256) {
        int o = i >> 6, c = i & 63;
        ws[c * 32 + o] = w1[i];
    }
}

// A: pixel-quad streaming conv. Thread = 4 consecutive pixels; per channel one
// float4 load (1KB/wave-inst). Two half-passes of acc[16][4] (pass B re-reads x
// from L2). 8-deep rotating prefetch buffer, all indices static after unroll.
__global__ __launch_bounds__(256) void conv_kernel(const float* __restrict__ x,
                                                   const float* __restrict__ w1t,
                                                   const float* __restrict__ b1,
                                                   u16* __restrict__ y) {
    int bid  = blockIdx.x;
    int b    = bid >> 6;            // 64 blocks per batch
    int h    = (bid & 63) * 4 + (threadIdx.x >> 6);   // wave = row
    int col4 = (threadIdx.x & 63) * 4;
    const f4v* xp = (const f4v*)(x + (size_t)b * NC * HW + (size_t)h * WW + col4);
    u16* yb = y + (size_t)b * (32 * HW) + (size_t)h * WW + col4;

    #pragma unroll 1
    for (int half = 0; half < 2; ++half) {
        float acc[16][4];
        #pragma unroll
        for (int j = 0; j < 16; j++) {
            float bj = b1[half * 16 + j];
            acc[j][0] = bj; acc[j][1] = bj; acc[j][2] = bj; acc[j][3] = bj;
        }

        f4v buf[8];
        #pragma unroll
        for (int i = 0; i < 8; i++) buf[i] = xp[(size_t)i * (HW / 4)];

        #pragma unroll
        for (int c = 0; c < 64; c++) {
            f4v xc = buf[c & 7];
            if (c < 56) buf[c & 7] = xp[(size_t)(c + 8) * (HW / 4)];
            #pragma unroll
            for (int j = 0; j < 16; j++) {
                float wj = w1t[c * 32 + half * 16 + j];
                acc[j][0] += wj * xc[0];
                acc[j][1] += wj * xc[1];
                acc[j][2] += wj * xc[2];
                acc[j][3] += wj * xc[3];
            }
        }

        #pragma unroll
        for (int j = 0; j < 16; j++) {
            u16x4 st;
            #pragma unroll
            for (int k = 0; k < 4; k++) {
                float v = fmaxf(acc[j][k], 0.f);
                __hip_bfloat16 hv = __float2bfloat16(v);
                st[k] = *reinterpret_cast<u16*>(&hv);
            }
            *(u16x4*)(yb + (size_t)(half * 16 + j) * HW) = st;
        }
    }
}

// B: block = one (b,o) plane (64KB of bf16). Wave-inst reads 1KB contiguous
// (u16x8/lane). Per thread: h%4 fixed, w%4 = j&3 static -> S[3][4] registers.
// Butterfly over 32-lane halves, LDS combine, threads 0..15 write qkv = mu+m3.
__global__ __launch_bounds__(256) void qkv_kernel(const u16* __restrict__ y,
                                                  float* __restrict__ qkv) {
    int g    = blockIdx.x;            // b*32 + o
    int t    = threadIdx.x;
    int wave = t >> 6;
    int lane = t & 63;
    int half = lane >> 5;
    int hres = (wave * 2 + half) & 3; // this thread's fixed h%4
    const u16x8* p = (const u16x8*)(y + (size_t)g * HW);

    float S1[4], S2[4], S3[4];
    #pragma unroll
    for (int j = 0; j < 4; j++) { S1[j] = 0.f; S2[j] = 0.f; S3[j] = 0.f; }

    #pragma unroll 4
    for (int k = 0; k < 32; ++k) {
        int h = k * 8 + wave * 2 + half;
        u16x8 v8 = p[h * 32 + (lane & 31)];
        #pragma unroll
        for (int j = 0; j < 8; j++) {
            unsigned int bits = (unsigned int)v8[j] << 16;
            float v = __builtin_bit_cast(float, bits);
            int wr = j & 3;
            S1[wr] += v;
            float pw = v * v;
            S2[wr] += pw;
            S3[wr] += pw * v;
        }
    }

    #pragma unroll
    for (int wr = 0; wr < 4; wr++) {
        #pragma unroll
        for (int m = 1; m <= 16; m <<= 1) {
            S1[wr] += __shfl_xor(S1[wr], m);
            S2[wr] += __shfl_xor(S2[wr], m);
            S3[wr] += __shfl_xor(S3[wr], m);
        }
    }

    __shared__ float red[2][4][4][3];   // [src][hres][wres][stat]
    if ((lane & 31) == 0) {
        int src = wave >> 1;
        #pragma unroll
        for (int wr = 0; wr < 4; wr++) {
            red[src][hres][wr][0] = S1[wr];
            red[src][hres][wr][1] = S2[wr];
            red[src][hres][wr][2] = S3[wr];
        }
    }
    __syncthreads();
    if (t < 16) {
        int hr = t >> 2, wr = t & 3;
        float s1 = red[0][hr][wr][0] + red[1][hr][wr][0];
        float s2 = red[0][hr][wr][1] + red[1][hr][wr][1];
        float s3 = red[0][hr][wr][2] + red[1][hr][wr][2];
        float mu = s1 * (1.f / 4096.f);
        float m3 = (s3 - 3.f * mu * s2 + 2.f * 4096.f * mu * mu * mu) * (1.f / 16.f);
        qkv[g * 16 + t] = mu + m3;     // t == hr*4+wr == s
    }
}

// Tiny attention: softmax(q q^T) @ v; gate = sigmoid(y).
__global__ __launch_bounds__(512) void attn_kernel(const float* __restrict__ qkvg,
                                                   float* __restrict__ gates) {
    int b = blockIdx.x;
    int t = threadIdx.x;
    __shared__ float qkv[512];
    qkv[t] = qkvg[b * 512 + t];
    __syncthreads();
    if (t < 256) {
        int o = t >> 4, s = t & 15;
        float qs = qkv[o * 16 + s];
        float mx = -1e30f;
        #pragma unroll
        for (int k = 0; k < 16; k++) mx = fmaxf(mx, qs * qkv[o * 16 + k]);
        float sum = 0.f, y = 0.f;
        #pragma unroll
        for (int k = 0; k < 16; k++) {
            float e = __expf(qs * qkv[o * 16 + k] - mx);
            sum += e;
            y   += e * qkv[(16 + o) * 16 + k];
        }
        y /= sum;
        float g = 1.f / (1.f + __expf(-y));
        gates[b * 256 + o * 16 + s] = g;
    }
}

// Per-pixel: recompute vx channels, gate, 16->64 conv, + bias + residual.
__global__ __launch_bounds__(256) void out_kernel(const float* __restrict__ x,
                                                  const float* __restrict__ w1t,
                                                  const float* __restrict__ b1,
                                                  const float* __restrict__ w2,
                                                  const float* __restrict__ b2,
                                                  const float* __restrict__ gates,
                                                  float* __restrict__ out) {
    int bh = blockIdx.x;
    int b  = bh >> 8;      // 256 rows per batch
    int h  = bh & 255;
    int w  = threadIdx.x;  // 0..255
    int s  = (h & 3) * 4 + (w & 3);
    const float* xb = x   + (size_t)b * NC * HW + h * WW + w;
    float*       ob = out + (size_t)b * NC * HW + h * WW + w;

    __shared__ float gsh[256];
    gsh[w] = gates[b * 256 + w];
    __syncthreads();

    float xr[64];
    #pragma unroll
    for (int c = 0; c < 64; c++) xr[c] = xb[(size_t)c * HW];

    float fv[16];
    #pragma unroll
    for (int j = 0; j < 16; j++) fv[j] = b1[16 + j];
    #pragma unroll
    for (int c = 0; c < 64; c++) {
        float xc = xr[c];
        #pragma unroll
        for (int j = 0; j < 16; j++) fv[j] += w1t[c * 32 + 16 + j] * xc;
    }
    #pragma unroll
    for (int j = 0; j < 16; j++) {
        float v = fv[j] > 0.f ? fv[j] : 0.f;
        fv[j] = v * gsh[j * 16 + s];
    }
    #pragma unroll
    for (int o = 0; o < 64; o++) {
        float r = b2[o] + xr[o];
        #pragma unroll
        for (int j = 0; j < 16; j++) r += w2[o * 16 + j] * fv[j];
        ob[(size_t)o * HW] = r;
    }
}

extern "C" void kernel_launch(void* const* d_in, const int* in_sizes, int n_in,
                              void* d_out, int out_size, void* d_ws, size_t ws_size,
                              hipStream_t stream) {
    const float* x  = (const float*)d_in[0];
    const float* w1 = (const float*)d_in[1];
    const float* b1 = (const float*)d_in[2];
    const float* w2 = (const float*)d_in[3];
    const float* b2 = (const float*)d_in[4];
    float* ws    = (float*)d_ws;
    float* w1t   = ws;
    float* qkv   = ws + 2048;
    float* gates = ws + 26624;
    u16*   y     = (u16*)(ws + 32768);
    float* out   = (float*)d_out;

    prep_kernel<<<1,    256, 0, stream>>>(w1, ws);
    conv_kernel<<<1024, 256, 0, stream>>>(x, w1t, b1, y);
    qkv_kernel <<<512,  256, 0, stream>>>(y, qkv);
    attn_kernel<<<16,   512, 0, stream>>>(qkv, gates);
    out_kernel <<<4096, 256, 0, stream>>>(x, w1t, b1, w2, b2, gates, out);
}

// Round 12
// 239.332 us; speedup vs baseline: 5.9639x; 5.9639x over previous
//
#include <hip/hip_runtime.h>
#include <hip/hip_bf16.h>

#define NB 16
#define NC 64
#define C2 32
#define C4 16
#define HH 256
#define WW 256
#define HW (HH*WW)          // 65536

typedef unsigned short u16;
typedef u16 u16x8 __attribute__((ext_vector_type(8)));
typedef u16 u16x2 __attribute__((ext_vector_type(2)));
typedef float f2v __attribute__((ext_vector_type(2)));

// ws layout (floats):
//   [0, 2048)        w1T   : w1T[c*32+o] = w1[o*64+c]
//   [2048, 10240)    qkv   : [b][ch32][s16]
//   [26624, 30720)   gates : [b][o16][s16]   (per-b stride 256)
//   [32768, ...)     y     : bf16 [b][o32][h256][w256]  (67.1 MB)

__global__ __launch_bounds__(256) void prep_kernel(const float* __restrict__ w1,
                                                   float* __restrict__ ws) {
    int t = threadIdx.x;
    for (int i = t; i < 2048; i += 256) {
        int o = i >> 6, c = i & 63;
        ws[c * 32 + o] = w1[i];
    }
}

// A: pixel-PAIR streaming conv. Thread = 2 adjacent pixels: float2 loads
// (512B/wave-inst), acc[32][2]=64 regs, dword stores. No manual prefetch —
// compiler hoists (out_kernel-proven); unroll 8 bounds the hoist window;
// launch_bounds(256,4) caps VGPR at 128 to prevent round-11's balloon.
__global__ __launch_bounds__(256, 4) void conv_kernel(const float* __restrict__ x,
                                                      const float* __restrict__ w1t,
                                                      const float* __restrict__ b1,
                                                      u16* __restrict__ y) {
    int bid = blockIdx.x;
    int b   = bid >> 7;                               // 128 blocks per batch
    int h   = (bid & 127) * 2 + (threadIdx.x >> 7);   // 2 rows per block
    int w2  = (threadIdx.x & 127) * 2;                // pixel pair
    const f2v* xp = (const f2v*)(x + (size_t)b * NC * HW + (size_t)h * WW + w2);
    u16* yb = y + (size_t)b * (32 * HW) + (size_t)h * WW + w2;

    float a0[32], a1[32];
    #pragma unroll
    for (int o = 0; o < 32; o++) { float bj = b1[o]; a0[o] = bj; a1[o] = bj; }

    #pragma unroll 8
    for (int c = 0; c < 64; c++) {
        f2v xc = xp[(size_t)c * (HW / 2)];
        #pragma unroll
        for (int o = 0; o < 32; o++) {
            float wj = w1t[c * 32 + o];
            a0[o] += wj * xc[0];
            a1[o] += wj * xc[1];
        }
    }

    #pragma unroll
    for (int o = 0; o < 32; o++) {
        float v0 = fmaxf(a0[o], 0.f);
        float v1 = fmaxf(a1[o], 0.f);
        __hip_bfloat16 h0 = __float2bfloat16(v0);
        __hip_bfloat16 h1 = __float2bfloat16(v1);
        u16x2 st;
        st[0] = *reinterpret_cast<u16*>(&h0);
        st[1] = *reinterpret_cast<u16*>(&h1);
        *(u16x2*)(yb + (size_t)o * HW) = st;
    }
}

// B: block = one (b,o) plane (64KB of bf16). Wave-inst reads 1KB contiguous
// (u16x8/lane). Per thread: h%4 fixed, w%4 = j&3 static -> S[3][4] registers.
// Butterfly over 32-lane halves, LDS combine, threads 0..15 write qkv = mu+m3.
__global__ __launch_bounds__(256) void qkv_kernel(const u16* __restrict__ y,
                                                  float* __restrict__ qkv) {
    int g    = blockIdx.x;            // b*32 + o
    int t    = threadIdx.x;
    int wave = t >> 6;
    int lane = t & 63;
    int half = lane >> 5;
    int hres = (wave * 2 + half) & 3; // this thread's fixed h%4
    const u16x8* p = (const u16x8*)(y + (size_t)g * HW);

    float S1[4], S2[4], S3[4];
    #pragma unroll
    for (int j = 0; j < 4; j++) { S1[j] = 0.f; S2[j] = 0.f; S3[j] = 0.f; }

    #pragma unroll 4
    for (int k = 0; k < 32; ++k) {
        int h = k * 8 + wave * 2 + half;
        u16x8 v8 = p[h * 32 + (lane & 31)];
        #pragma unroll
        for (int j = 0; j < 8; j++) {
            unsigned int bits = (unsigned int)v8[j] << 16;
            float v = __builtin_bit_cast(float, bits);
            int wr = j & 3;
            S1[wr] += v;
            float pw = v * v;
            S2[wr] += pw;
            S3[wr] += pw * v;
        }
    }

    #pragma unroll
    for (int wr = 0; wr < 4; wr++) {
        #pragma unroll
        for (int m = 1; m <= 16; m <<= 1) {
            S1[wr] += __shfl_xor(S1[wr], m);
            S2[wr] += __shfl_xor(S2[wr], m);
            S3[wr] += __shfl_xor(S3[wr], m);
        }
    }

    __shared__ float red[2][4][4][3];   // [src][hres][wres][stat]
    if ((lane & 31) == 0) {
        int src = wave >> 1;
        #pragma unroll
        for (int wr = 0; wr < 4; wr++) {
            red[src][hres][wr][0] = S1[wr];
            red[src][hres][wr][1] = S2[wr];
            red[src][hres][wr][2] = S3[wr];
        }
    }
    __syncthreads();
    if (t < 16) {
        int hr = t >> 2, wr = t & 3;
        float s1 = red[0][hr][wr][0] + red[1][hr][wr][0];
        float s2 = red[0][hr][wr][1] + red[1][hr][wr][1];
        float s3 = red[0][hr][wr][2] + red[1][hr][wr][2];
        float mu = s1 * (1.f / 4096.f);
        float m3 = (s3 - 3.f * mu * s2 + 2.f * 4096.f * mu * mu * mu) * (1.f / 16.f);
        qkv[g * 16 + t] = mu + m3;     // t == hr*4+wr == s
    }
}

// Tiny attention: softmax(q q^T) @ v; gate = sigmoid(y).
__global__ __launch_bounds__(512) void attn_kernel(const float* __restrict__ qkvg,
                                                   float* __restrict__ gates) {
    int b = blockIdx.x;
    int t = threadIdx.x;
    __shared__ float qkv[512];
    qkv[t] = qkvg[b * 512 + t];
    __syncthreads();
    if (t < 256) {
        int o = t >> 4, s = t & 15;
        float qs = qkv[o * 16 + s];
        float mx = -1e30f;
        #pragma unroll
        for (int k = 0; k < 16; k++) mx = fmaxf(mx, qs * qkv[o * 16 + k]);
        float sum = 0.f, y = 0.f;
        #pragma unroll
        for (int k = 0; k < 16; k++) {
            float e = __expf(qs * qkv[o * 16 + k] - mx);
            sum += e;
            y   += e * qkv[(16 + o) * 16 + k];
        }
        y /= sum;
        float g = 1.f / (1.f + __expf(-y));
        gates[b * 256 + o * 16 + s] = g;
    }
}

// Per-pixel: recompute vx channels, gate, 16->64 conv, + bias + residual.
__global__ __launch_bounds__(256) void out_kernel(const float* __restrict__ x,
                                                  const float* __restrict__ w1t,
                                                  const float* __restrict__ b1,
                                                  const float* __restrict__ w2,
                                                  const float* __restrict__ b2,
                                                  const float* __restrict__ gates,
                                                  float* __restrict__ out) {
    int bh = blockIdx.x;
    int b  = bh >> 8;      // 256 rows per batch
    int h  = bh & 255;
    int w  = threadIdx.x;  // 0..255
    int s  = (h & 3) * 4 + (w & 3);
    const float* xb = x   + (size_t)b * NC * HW + h * WW + w;
    float*       ob = out + (size_t)b * NC * HW + h * WW + w;

    __shared__ float gsh[256];
    gsh[w] = gates[b * 256 + w];
    __syncthreads();

    float xr[64];
    #pragma unroll
    for (int c = 0; c < 64; c++) xr[c] = xb[(size_t)c * HW];

    float fv[16];
    #pragma unroll
    for (int j = 0; j < 16; j++) fv[j] = b1[16 + j];
    #pragma unroll
    for (int c = 0; c < 64; c++) {
        float xc = xr[c];
        #pragma unroll
        for (int j = 0; j < 16; j++) fv[j] += w1t[c * 32 + 16 + j] * xc;
    }
    #pragma unroll
    for (int j = 0; j < 16; j++) {
        float v = fv[j] > 0.f ? fv[j] : 0.f;
        fv[j] = v * gsh[j * 16 + s];
    }
    #pragma unroll
    for (int o = 0; o < 64; o++) {
        float r = b2[o] + xr[o];
        #pragma unroll
        for (int j = 0; j < 16; j++) r += w2[o * 16 + j] * fv[j];
        ob[(size_t)o * HW] = r;
    }
}

extern "C" void kernel_launch(void* const* d_in, const int* in_sizes, int n_in,
                              void* d_out, int out_size, void* d_ws, size_t ws_size,
                              hipStream_t stream) {
    const float* x  = (const float*)d_in[0];
    const float* w1 = (const float*)d_in[1];
    const float* b1 = (const float*)d_in[2];
    const float* w2 = (const float*)d_in[3];
    const float* b2 = (const float*)d_in[4];
    float* ws    = (float*)d_ws;
    float* w1t   = ws;
    float* qkv   = ws + 2048;
    float* gates = ws + 26624;
    u16*   y     = (u16*)(ws + 32768);
    float* out   = (float*)d_out;

    prep_kernel<<<1,    256, 0, stream>>>(w1, ws);
    conv_kernel<<<2048, 256, 0, stream>>>(x, w1t, b1, y);
    qkv_kernel <<<512,  256, 0, stream>>>(y, qkv);
    attn_kernel<<<16,   512, 0, stream>>>(qkv, gates);
    out_kernel <<<4096, 256, 0, stream>>>(x, w1t, b1, w2, b2, gates, out);
}